// Round 11
// baseline (274.529 us; speedup 1.0000x reference)
//
#include <hip/hip_runtime.h>
#include <hip/hip_bf16.h>

#define D 128
#define SCAN_BLK 256
#define SCAN_VPT 4
#define SCAN_TILE (SCAN_BLK * SCAN_VPT)   // 1024 nodes per scan block

typedef __attribute__((ext_vector_type(8))) short short8;   // 8 bf16 = 4 VGPR
typedef __attribute__((ext_vector_type(4))) float f32x4;    // MFMA C/D frag

// ---------------------------------------------------------------------------
// prep_w: WTl/WTr = bf16 transpose of Wl/Wr; bsum = bl + br; PLUS the full
// degree histogram (moved out of the GEMM to isolate its cost — deg is
// zeroed by a preceding hipMemsetAsync, so no zero/atomic race here).
// ---------------------------------------------------------------------------
__global__ __launch_bounds__(256) void prep_w(
    const float* __restrict__ Wl, const float* __restrict__ Wr,
    const float* __restrict__ bl, const float* __restrict__ br,
    __hip_bfloat16* __restrict__ WTl, __hip_bfloat16* __restrict__ WTr,
    float* __restrict__ bsum,
    const int* __restrict__ edst, int* __restrict__ deg, int n_edges) {
  const int tid = blockIdx.x * 256 + threadIdx.x;  // grid 512 -> 0..131071
  if (tid < 16384) {
    const int n = (tid >> 7) & 127;
    const int k = tid & 127;
    WTl[n * D + k] = __float2bfloat16(Wl[k * D + n]);
  } else if (tid < 32768) {
    const int n = (tid >> 7) & 127;
    const int k = tid & 127;
    WTr[n * D + k] = __float2bfloat16(Wr[k * D + n]);
  }
  if (tid < 128) bsum[tid] = bl[tid] + br[tid];

  const int gsz = gridDim.x * 256;
  for (int e = tid; e < n_edges; e += gsz)
    atomicAdd(&deg[edst[e]], 1);
}

// ---------------------------------------------------------------------------
// gemm_hr (PURE): h = bf16(x @ Wl) AND out = x @ Wr + bsum. One 16-row tile
// per block (grid 6250), no grid-stride loop, single barrier. B-frags loaded
// once per block from L2-hot tables, reused by both MFMAs.
// ---------------------------------------------------------------------------
__global__ __launch_bounds__(256) void gemm_hr(
    const float* __restrict__ x, const __hip_bfloat16* __restrict__ WTl,
    const __hip_bfloat16* __restrict__ WTr, const float* __restrict__ bsum,
    __hip_bfloat16* __restrict__ h, float* __restrict__ out) {
  __shared__ __hip_bfloat16 xs[16][136];   // +8 pad
  const int t = threadIdx.x;
  const int wave = t >> 6;
  const int lane = t & 63;
  const int m = lane & 15;
  const int q = lane >> 4;
  const int rowbase = blockIdx.x * 16;

  // B fragments + bias (L2-resident tables; independent of the x staging)
  short8 bfl[2][4], bfr[2][4];
  float bias[2];
#pragma unroll
  for (int c = 0; c < 2; ++c) {
    const int n0 = wave * 32 + c * 16;
    bias[c] = bsum[n0 + m];
#pragma unroll
    for (int ks = 0; ks < 4; ++ks) {
      bfl[c][ks] = *(const short8*)&WTl[(n0 + m) * D + ks * 32 + q * 8];
      bfr[c][ks] = *(const short8*)&WTr[(n0 + m) * D + ks * 32 + q * 8];
    }
  }

  // stage 16x128 fp32 -> bf16
  {
    const int srow = t >> 4;
    const int scol = (t & 15) * 8;
    const float4* src = (const float4*)&x[(size_t)(rowbase + srow) * D + scol];
    const float4 v0 = src[0], v1 = src[1];
    __hip_bfloat16* dst = &xs[srow][scol];
    dst[0] = __float2bfloat16(v0.x); dst[1] = __float2bfloat16(v0.y);
    dst[2] = __float2bfloat16(v0.z); dst[3] = __float2bfloat16(v0.w);
    dst[4] = __float2bfloat16(v1.x); dst[5] = __float2bfloat16(v1.y);
    dst[6] = __float2bfloat16(v1.z); dst[7] = __float2bfloat16(v1.w);
  }
  __syncthreads();

  f32x4 accL[2], accR[2];
#pragma unroll
  for (int c = 0; c < 2; ++c)
#pragma unroll
    for (int r = 0; r < 4; ++r) { accL[c][r] = 0.f; accR[c][r] = 0.f; }

#pragma unroll
  for (int ks = 0; ks < 4; ++ks) {
    const short8 afrag = *(const short8*)&xs[m][ks * 32 + q * 8];
#pragma unroll
    for (int c = 0; c < 2; ++c) {
      accL[c] = __builtin_amdgcn_mfma_f32_16x16x32_bf16(afrag, bfl[c][ks], accL[c], 0, 0, 0);
      accR[c] = __builtin_amdgcn_mfma_f32_16x16x32_bf16(afrag, bfr[c][ks], accR[c], 0, 0, 0);
    }
  }

#pragma unroll
  for (int c = 0; c < 2; ++c) {
    const int n = wave * 32 + c * 16 + m;
#pragma unroll
    for (int r = 0; r < 4; ++r) {
      const size_t row = (size_t)(rowbase + q * 4 + r);
      h[row * D + n] = __float2bfloat16(accL[c][r]);
      out[row * D + n] = accR[c][r] + bias[c];
    }
  }
}

// ---------------------------------------------------------------------------
// scan_ll: single-pass decoupled-lookback exclusive scan of deg -> offsets
// and pos cursors (proven round 8). 98 blocks <= CU count -> co-resident.
// ---------------------------------------------------------------------------
__global__ __launch_bounds__(SCAN_BLK) void scan_ll(
    int* __restrict__ pos /* deg in, cursors out */, int* __restrict__ offsets,
    unsigned long long* __restrict__ state, int n, int n_edges) {
  __shared__ int sdata[SCAN_BLK];
  __shared__ int s_prefix;
  const int t = threadIdx.x;
  const int b = blockIdx.x;
  const int base = b * SCAN_TILE + t * SCAN_VPT;

  int v[SCAN_VPT];
  int s = 0;
#pragma unroll
  for (int j = 0; j < SCAN_VPT; ++j) {
    v[j] = (base + j < n) ? pos[base + j] : 0;
    s += v[j];
  }
  sdata[t] = s;
  __syncthreads();
  for (int off = 1; off < SCAN_BLK; off <<= 1) {
    int xv = (t >= off) ? sdata[t - off] : 0;
    __syncthreads();
    sdata[t] += xv;
    __syncthreads();
  }
  const int excl = sdata[t] - s;
  const int total = sdata[SCAN_BLK - 1];

  if (t == 0) {
    const unsigned long long st =
        ((unsigned long long)(b == 0 ? 2 : 1) << 62) | (unsigned int)total;
    __hip_atomic_store(&state[b], st, __ATOMIC_RELEASE, __HIP_MEMORY_SCOPE_AGENT);
  }

  if (b == 0) {
    if (t == 0) s_prefix = 0;
  } else if (t < 64) {
    int windowEnd = b;
    int acc = 0;
    for (;;) {
      const int j = windowEnd - 1 - t;
      unsigned long long st = 0;
      if (j >= 0) {
        do {
          st = __hip_atomic_load(&state[j], __ATOMIC_ACQUIRE, __HIP_MEMORY_SCOPE_AGENT);
        } while (st == 0);
      }
      const int flag = (j >= 0) ? (int)(st >> 62) : 2;
      const int val = (j >= 0) ? (int)(st & 0xffffffffull) : 0;
      const unsigned long long mask = __ballot(flag == 2);
      if (mask) {
        const int firstLane = __ffsll((long long)mask) - 1;
        int contrib = (t <= firstLane) ? val : 0;
#pragma unroll
        for (int o = 32; o > 0; o >>= 1) contrib += __shfl_down(contrib, o);
        if (t == 0) { acc += contrib; s_prefix = acc; }
        break;
      } else {
        int contrib = val;
#pragma unroll
        for (int o = 32; o > 0; o >>= 1) contrib += __shfl_down(contrib, o);
        if (t == 0) acc += contrib;
        windowEnd -= 64;
      }
    }
  }
  __syncthreads();
  const int add = s_prefix;

  if (t == 0 && b > 0) {
    const unsigned long long st = (2ull << 62) | (unsigned int)(add + total);
    __hip_atomic_store(&state[b], st, __ATOMIC_RELEASE, __HIP_MEMORY_SCOPE_AGENT);
  }

  int run = add + excl;
#pragma unroll
  for (int j = 0; j < SCAN_VPT; ++j) {
    if (base + j < n) {
      offsets[base + j] = run;
      pos[base + j] = run;
    }
    run += v[j];
  }
  if (b == 0 && t == 0) offsets[n] = n_edges;
}

// ---------------------------------------------------------------------------
// scatter: pairs[slot] = {src, bits(weight)} in dst-sorted order.
// ---------------------------------------------------------------------------
__global__ __launch_bounds__(256) void scatter_kernel(
    const int* __restrict__ esrc, const int* __restrict__ edst,
    const float* __restrict__ ew, int* __restrict__ pos,
    int2* __restrict__ pairs, int n_edges) {
  const int e = blockIdx.x * 256 + threadIdx.x;
  if (e >= n_edges) return;
  const int d = edst[e];
  const int slot = atomicAdd(&pos[d], 1);
  pairs[slot] = make_int2(esrc[e], __float_as_int(ew[e]));
}

// ---------------------------------------------------------------------------
// sage_agg: pure gather-accumulate (v6, proven). One node per wave, no LDS,
// no barriers. a = out_row (root); masked 8-deep batch covers avg degree-6
// in one latency round (clamp + zero weight keeps exact accumulation order).
// ---------------------------------------------------------------------------
__global__ __launch_bounds__(256) void sage_agg(
    const __hip_bfloat16* __restrict__ h,
    const int* __restrict__ offsets, const int2* __restrict__ pairs,
    float* __restrict__ out, int n_nodes) {
  const int node = blockIdx.x * 4 + (threadIdx.x >> 6);
  const int lane = threadIdx.x & 63;
  if (node >= n_nodes) return;
  const int begin = offsets[node];
  const int end = offsets[node + 1];
  const __hip_bfloat162* __restrict__ h2 = (const __hip_bfloat162*)h;

  float2 a = *(const float2*)&out[(size_t)node * D + 2 * lane];

  int i = begin;
  for (; i + 8 <= end; i += 8) {
    int2 p[8];
#pragma unroll
    for (int u = 0; u < 8; ++u) p[u] = pairs[i + u];
    __hip_bfloat162 hv[8];
#pragma unroll
    for (int u = 0; u < 8; ++u)
      hv[u] = h2[(size_t)p[u].x * (D / 2) + lane];
#pragma unroll
    for (int u = 0; u < 8; ++u) {
      const float w = __int_as_float(p[u].y);
      a.x = fmaf(w, __bfloat162float(hv[u].x), a.x);
      a.y = fmaf(w, __bfloat162float(hv[u].y), a.y);
    }
  }
  if (i < end) {
    int2 p[8];
#pragma unroll
    for (int u = 0; u < 8; ++u) {
      const int ei = (i + u < end) ? (i + u) : (end - 1);   // clamp (valid)
      p[u] = pairs[ei];
      if (i + u >= end) p[u].y = 0;                         // w = 0.0f
    }
    __hip_bfloat162 hv[8];
#pragma unroll
    for (int u = 0; u < 8; ++u)
      hv[u] = h2[(size_t)p[u].x * (D / 2) + lane];
#pragma unroll
    for (int u = 0; u < 8; ++u) {
      const float w = __int_as_float(p[u].y);
      a.x = fmaf(w, __bfloat162float(hv[u].x), a.x);
      a.y = fmaf(w, __bfloat162float(hv[u].y), a.y);
    }
  }

  *(float2*)&out[(size_t)node * D + 2 * lane] = a;
}

// ---------------------------------------------------------------------------
extern "C" void kernel_launch(void* const* d_in, const int* in_sizes, int n_in,
                              void* d_out, int out_size, void* d_ws, size_t ws_size,
                              hipStream_t stream) {
  const float* x   = (const float*)d_in[0];
  const int* esrc  = (const int*)d_in[1];
  const int* edst  = (const int*)d_in[2];
  const float* ew  = (const float*)d_in[3];
  const float* Wl  = (const float*)d_in[4];
  const float* bl  = (const float*)d_in[5];
  const float* Wr  = (const float*)d_in[6];
  const float* br  = (const float*)d_in[7];
  float* out = (float*)d_out;

  const int n_nodes = in_sizes[0] / D;   // 100000
  const int n_edges = in_sizes[1];       // 600000

  // Workspace layout (16B aligned sections). pos and state are contiguous so
  // one memset clears both (deg zero + lookback-state zero).
  char* ws = (char*)d_ws;
  size_t off = 0;
  __hip_bfloat16* h = (__hip_bfloat16*)(ws + off);      // 25.6 MB
  off += (size_t)n_nodes * D * sizeof(__hip_bfloat16);
  off = (off + 15) & ~15ull;
  int* offsets = (int*)(ws + off);
  off += (size_t)(n_nodes + 1) * sizeof(int);
  off = (off + 15) & ~15ull;
  int* pos = (int*)(ws + off);                          // degree, then cursors
  size_t pos_off = off;
  off += (size_t)n_nodes * sizeof(int);
  off = (off + 15) & ~15ull;
  unsigned long long* state = (unsigned long long*)(ws + off);  // lookback
  off += 1024 * sizeof(unsigned long long);
  size_t zero_bytes = off - pos_off;                    // pos + pad + state
  off = (off + 15) & ~15ull;
  int2* pairs = (int2*)(ws + off);                      // 4.8 MB
  off += (size_t)n_edges * sizeof(int2);
  off = (off + 15) & ~15ull;
  __hip_bfloat16* WTl = (__hip_bfloat16*)(ws + off);
  off += (size_t)D * D * sizeof(__hip_bfloat16);
  __hip_bfloat16* WTr = (__hip_bfloat16*)(ws + off);
  off += (size_t)D * D * sizeof(__hip_bfloat16);
  float* bsum = (float*)(ws + off);
  off += D * sizeof(float);

  hipMemsetAsync(pos, 0, zero_bytes, stream);

  prep_w<<<512, 256, 0, stream>>>(Wl, Wr, bl, br, WTl, WTr, bsum, edst, pos, n_edges);

  const int n_rowtiles = (n_nodes + 15) / 16;           // 6250 (exact)
  gemm_hr<<<n_rowtiles, 256, 0, stream>>>(x, WTl, WTr, bsum, h, out);

  const int nparts = (n_nodes + SCAN_TILE - 1) / SCAN_TILE;   // 98
  scan_ll<<<nparts, SCAN_BLK, 0, stream>>>(pos, offsets, state, n_nodes, n_edges);

  scatter_kernel<<<(n_edges + 255) / 256, 256, 0, stream>>>(esrc, edst, ew, pos, pairs, n_edges);

  sage_agg<<<(n_nodes + 3) / 4, 256, 0, stream>>>(h, offsets, pairs, out, n_nodes);
}